// Round 4
// baseline (48.582 us; speedup 1.0000x reference)
//
#include <hip/hip_runtime.h>
#include <math.h>

// CTC batch cost. Two-kernel pipeline:
//  K1 (8192 blocks, one per (b,t)): stream the full 16KB y_pred row through
//     LDS (coalesced float4), then 49 lanes extract log2(p[cls]+eps) -> ws.
//     Turns the random gather into a streaming read (L3-resident across
//     replays), avoiding the per-CU outstanding-miss bottleneck.
//  K2 (64 blocks x 64 threads): stage [T][49] slice into LDS, wave-register
//     DP over T with DPP wave_shr:1 and prefetch distance 4.
// Falls back to a fused single kernel if ws_size is too small.

#define NEGV (-1e30f)
#define EPSV (1e-7f)

constexpr int B = 64, T = 128, C = 4000, L = 48;
constexpr int BLANK = C - 1;       // 3999
constexpr int NCLS = L + 1;        // 49: slots 0..47 = labels, 48 = blank
constexpr int TOTAL = B * T * NCLS;

// lane shift up by 1 across the full wave via DPP wave_shr:1 (VALU latency).
// Lane 0 receives `old`.
__device__ __forceinline__ float dpp_shr1_neg(float x) {
    int r = __builtin_amdgcn_update_dpp(__float_as_int(NEGV), __float_as_int(x),
                                        0x138 /*wave_shr:1*/, 0xF, 0xF, false);
    return __int_as_float(r);
}
__device__ __forceinline__ int dpp_shr1_i(int x, int old) {
    return __builtin_amdgcn_update_dpp(old, x, 0x138, 0xF, 0xF, false);
}

// ---------------- Kernel 1: streaming row extraction ----------------
__global__ __launch_bounds__(256) void gather_stream(
    const int* __restrict__ y_true,     // [B, L]
    const float* __restrict__ y_pred,   // [B, T, C]
    const int* __restrict__ label_len,  // [B, 1]
    float* __restrict__ lp_ws)          // [B, T, NCLS] log2-probs
{
    const int bt = blockIdx.x;          // bt = b*T + t
    const int b = bt >> 7;              // T = 128
    const int tid = threadIdx.x;

    __shared__ float row[C];            // 16000 B

    // class for this lane's output slot (loads hidden under the row stream)
    int cls = BLANK;
    if (tid < NCLS) {
        int ll = label_len[b];
        if (tid < L) {
            int v = y_true[b * L + tid];
            cls = (tid < ll) ? v : BLANK;
        }
    }

    // coalesced full-row read: 1000 float4
    const float4* src = (const float4*)(y_pred + (size_t)bt * C);
    float4* dstv = (float4*)row;
    #pragma unroll
    for (int i = 0; i < 4; ++i) {
        int idx = tid + i * 256;
        if (idx < C / 4) dstv[idx] = src[idx];
    }
    __syncthreads();

    if (tid < NCLS)
        lp_ws[(size_t)bt * NCLS + tid] = log2f(row[cls] + EPSV);
}

// ---------------- Kernel 2: DP (one wave per batch element) ----------------
__global__ __launch_bounds__(64) void dp_kernel(
    const int* __restrict__ y_true,
    const int* __restrict__ label_len,
    const float* __restrict__ lp_ws,    // [B, T, NCLS]
    float* __restrict__ out)            // [B, 1]
{
    const int b = blockIdx.x;
    const int lane = threadIdx.x;

    __shared__ float lp_s[T * NCLS + 32];   // +pad so lane<=63 reads stay in-bounds

    const int ll = label_len[b];            // uniform broadcast load

    int myLab = BLANK;
    if (lane < L) {
        int v = y_true[b * L + lane];
        myLab = (lane < ll) ? v : BLANK;    // pad with blank as reference
    }

    // stage 6272 floats = 1568 float4, single wave
    const float4* src = (const float4*)(lp_ws + (size_t)b * T * NCLS);
    float4* dst = (float4*)lp_s;
    for (int i = lane; i < (T * NCLS) / 4; i += 64) dst[i] = src[i];
    __syncthreads();

    const int prevLab = dpp_shr1_i(myLab, BLANK);
    const bool allow2 = (lane >= 1) && (myLab != BLANK) && (myLab != prevLab);

    float a0 = (lane == 0) ? lp_s[48] : NEGV;   // t=0, state 0 (blank)
    float a1 = (lane == 0) ? lp_s[0]  : NEGV;   // t=0, state 1 (label 0)

    const int lidx = (lane < NCLS) ? lane : 48; // clamp (pad covers anyway)

    // rolling prefetch, distance 4
    float lpb_f[4], lpl_f[4];
    #pragma unroll
    for (int k = 0; k < 4; ++k) {
        int tt = 1 + k;
        lpb_f[k] = lp_s[tt * NCLS + 48];
        lpl_f[k] = lp_s[tt * NCLS + lidx];
    }

    #pragma unroll 4
    for (int t = 1; t < T; ++t) {
        const int k = (t - 1) & 3;              // constant per unrolled copy
        float lpb = lpb_f[k];
        float lpl = (lane < L) ? lpl_f[k] : 0.0f;
        int tp = t + 4;
        if (tp < T) {
            lpb_f[k] = lp_s[tp * NCLS + 48];
            lpl_f[k] = lp_s[tp * NCLS + lidx];
        }

        float pa1 = dpp_shr1_neg(a1);           // alpha[2l-1] from lane l-1

        // state 2l: lse2(a0, pa1) + lpb  ((m0+lpb) runs parallel to exp/log)
        float m0 = fmaxf(a0, pa1);
        float n0 = fminf(a0, pa1);
        float r0 = (m0 + lpb) + log2f(1.0f + exp2f(n0 - m0));

        // state 2l+1: lse3(a1, a0, allow2 ? pa1 : NEG) + lpl
        float c12 = allow2 ? pa1 : NEGV;
        float m1 = fmaxf(fmaxf(a1, a0), c12);
        float r1 = (m1 + lpl) + log2f(exp2f(a1 - m1) + exp2f(a0 - m1) +
                                      exp2f(c12 - m1));

        a0 = r0;
        a1 = (lane < L) ? r1 : NEGV;            // states beyond S stay dead
    }

    float ab = __shfl(a0, ll);          // alpha[2*ll]
    float al = __shfl(a1, ll - 1);      // alpha[2*ll-1]
    if (lane == 0) {
        float m = fmaxf(ab, al);
        float ll2 = m + log2f(exp2f(ab - m) + exp2f(al - m));
        out[b] = -ll2 * 0.69314718055994531f;   // back to natural log
    }
}

// ---------------- Fallback: fused single kernel (small ws) ----------------
__global__ __launch_bounds__(256) void ctc_fused_kernel(
    const int* __restrict__ y_true,
    const float* __restrict__ y_pred,
    const int* __restrict__ label_len,
    float* __restrict__ out)
{
    const int b = blockIdx.x;
    const int tid = threadIdx.x;

    __shared__ float lp_s[T * NCLS + 32];
    __shared__ int   lab_s[L];
    __shared__ int   ll_s;

    if (tid < L) {
        int ll = label_len[b];
        if (tid == 0) ll_s = ll;
        int v = y_true[b * L + tid];
        lab_s[tid] = (tid < ll) ? v : BLANK;
    }
    __syncthreads();

    const float* yp = y_pred + (size_t)b * T * C;
    for (int g = tid; g < T * NCLS; g += 256) {
        int t = g / NCLS;
        int j = g - t * NCLS;
        int cls = (j < L) ? lab_s[j] : BLANK;
        lp_s[g] = log2f(yp[t * C + cls] + EPSV);
    }
    __syncthreads();

    if (tid >= 64) return;
    const int lane = tid;
    const int ll = ll_s;
    const int myLab   = (lane < L) ? lab_s[lane] : BLANK;
    const int prevLab = (lane >= 1 && lane - 1 < L) ? lab_s[lane - 1] : BLANK;
    const bool allow2 = (lane >= 1) && (myLab != BLANK) && (myLab != prevLab);

    float a0 = (lane == 0) ? lp_s[48] : NEGV;
    float a1 = (lane == 0) ? lp_s[0]  : NEGV;

    for (int t = 1; t < T; ++t) {
        float lpb = lp_s[t * NCLS + 48];
        float lpl = (lane < L) ? lp_s[t * NCLS + lane] : 0.0f;

        float pa1 = dpp_shr1_neg(a1);

        float m0 = fmaxf(a0, pa1);
        float n0 = fminf(a0, pa1);
        float r0 = (m0 + lpb) + log2f(1.0f + exp2f(n0 - m0));

        float c12 = allow2 ? pa1 : NEGV;
        float m1 = fmaxf(fmaxf(a1, a0), c12);
        float r1 = (m1 + lpl) + log2f(exp2f(a1 - m1) + exp2f(a0 - m1) +
                                      exp2f(c12 - m1));

        a0 = r0;
        a1 = (lane < L) ? r1 : NEGV;
    }

    float ab = __shfl(a0, ll);
    float al = __shfl(a1, ll - 1);
    if (lane == 0) {
        float m = fmaxf(ab, al);
        float ll2 = m + log2f(exp2f(ab - m) + exp2f(al - m));
        out[b] = -ll2 * 0.69314718055994531f;
    }
}

extern "C" void kernel_launch(void* const* d_in, const int* in_sizes, int n_in,
                              void* d_out, int out_size, void* d_ws, size_t ws_size,
                              hipStream_t stream) {
    const int*   y_true       = (const int*)d_in[0];
    const float* y_pred       = (const float*)d_in[1];
    const int*   label_length = (const int*)d_in[2];
    float*       out          = (float*)d_out;

    const size_t need = (size_t)TOTAL * sizeof(float);
    if (ws_size >= need) {
        float* lp_ws = (float*)d_ws;
        gather_stream<<<B * T, 256, 0, stream>>>(y_true, y_pred, label_length, lp_ws);
        dp_kernel<<<B, 64, 0, stream>>>(y_true, label_length, lp_ws, out);
    } else {
        ctc_fused_kernel<<<B, 256, 0, stream>>>(y_true, y_pred, label_length, out);
    }
}

// Round 5
// 36.869 us; speedup vs baseline: 1.3177x; 1.3177x over previous
//
#include <hip/hip_runtime.h>
#include <math.h>

// CTC batch cost. Three-kernel pipeline:
//  K0 (64 blocks): precompute cls[b][j] (padded labels + blank) -> ws.
//  K1 (392 blocks): random-gather log2(y_pred[b,t,cls]+eps), 4 independent
//     gathers per thread (MLP), coalesced cls reads / lp writes.
//  K2 (64 blocks x 64 threads): stage [T][49] slice into LDS, wave-register
//     DP over T with DPP wave_shr:1 and prefetch distance 4.
// Falls back to a fused single kernel if ws_size is too small.

#define NEGV (-1e30f)
#define EPSV (1e-7f)

constexpr int B = 64, T = 128, C = 4000, L = 48;
constexpr int BLANK = C - 1;       // 3999
constexpr int NCLS = L + 1;        // 49: slots 0..47 = labels, 48 = blank
constexpr int TOTAL = B * T * NCLS;  // 401408 = 392 * 1024 exactly

// lane shift up by 1 across the full wave via DPP wave_shr:1 (VALU latency).
// Lane 0 receives `old`.
__device__ __forceinline__ float dpp_shr1_neg(float x) {
    int r = __builtin_amdgcn_update_dpp(__float_as_int(NEGV), __float_as_int(x),
                                        0x138 /*wave_shr:1*/, 0xF, 0xF, false);
    return __int_as_float(r);
}
__device__ __forceinline__ int dpp_shr1_i(int x, int old) {
    return __builtin_amdgcn_update_dpp(old, x, 0x138, 0xF, 0xF, false);
}

// ---------------- Kernel 0: class table ----------------
__global__ __launch_bounds__(64) void cls_kernel(
    const int* __restrict__ y_true,     // [B, L]
    const int* __restrict__ label_len,  // [B, 1]
    int* __restrict__ cls_tab)          // [B, NCLS]
{
    const int b = blockIdx.x;
    const int j = threadIdx.x;
    if (j >= NCLS) return;
    int cls = BLANK;
    if (j < L) {
        int ll = label_len[b];
        int v = y_true[b * L + j];
        cls = (j < ll) ? v : BLANK;     // pad beyond label_length with blank
    }
    cls_tab[b * NCLS + j] = cls;
}

// ---------------- Kernel 1: gather, 4-way MLP ----------------
__global__ __launch_bounds__(256) void gather4_kernel(
    const int* __restrict__ cls_tab,    // [B, NCLS]
    const float* __restrict__ y_pred,   // [B, T, C]
    float* __restrict__ lp_ws)          // [B, T, NCLS] log2-probs
{
    const int base = blockIdx.x * 1024 + threadIdx.x;

    int cls[4];
    #pragma unroll
    for (int i = 0; i < 4; ++i) {
        int idx = base + i * 256;
        int bt = idx / NCLS;
        int j  = idx - bt * NCLS;
        int b  = bt >> 7;               // T = 128
        cls[i] = cls_tab[b * NCLS + j]; // L2-hot (12.5 KB table)
    }
    float p[4];
    #pragma unroll
    for (int i = 0; i < 4; ++i) {
        int idx = base + i * 256;
        int bt = idx / NCLS;
        p[i] = y_pred[(size_t)bt * C + cls[i]];   // 4 independent HBM gathers
    }
    #pragma unroll
    for (int i = 0; i < 4; ++i)
        lp_ws[base + i * 256] = log2f(p[i] + EPSV);
}

// ---------------- Kernel 2: DP (one wave per batch element) ----------------
__global__ __launch_bounds__(64) void dp_kernel(
    const int* __restrict__ cls_tab,    // [B, NCLS]
    const int* __restrict__ label_len,
    const float* __restrict__ lp_ws,    // [B, T, NCLS]
    float* __restrict__ out)            // [B, 1]
{
    const int b = blockIdx.x;
    const int lane = threadIdx.x;

    __shared__ float lp_s[T * NCLS + 32];   // +pad so lane<=63 reads stay in-bounds

    const int ll = label_len[b];            // uniform broadcast load

    int myLab = BLANK;
    if (lane < L) myLab = cls_tab[b * NCLS + lane];  // already padded with blank

    // stage 6272 floats = 1568 float4, single wave
    const float4* src = (const float4*)(lp_ws + (size_t)b * T * NCLS);
    float4* dst = (float4*)lp_s;
    for (int i = lane; i < (T * NCLS) / 4; i += 64) dst[i] = src[i];
    __syncthreads();

    const int prevLab = dpp_shr1_i(myLab, BLANK);
    const bool allow2 = (lane >= 1) && (myLab != BLANK) && (myLab != prevLab);

    float a0 = (lane == 0) ? lp_s[48] : NEGV;   // t=0, state 0 (blank)
    float a1 = (lane == 0) ? lp_s[0]  : NEGV;   // t=0, state 1 (label 0)

    const int lidx = (lane < NCLS) ? lane : 48; // clamp (pad covers anyway)

    // rolling prefetch, distance 4
    float lpb_f[4], lpl_f[4];
    #pragma unroll
    for (int k = 0; k < 4; ++k) {
        int tt = 1 + k;
        lpb_f[k] = lp_s[tt * NCLS + 48];
        lpl_f[k] = lp_s[tt * NCLS + lidx];
    }

    #pragma unroll 4
    for (int t = 1; t < T; ++t) {
        const int k = (t - 1) & 3;              // constant per unrolled copy
        float lpb = lpb_f[k];
        float lpl = (lane < L) ? lpl_f[k] : 0.0f;
        int tp = t + 4;
        if (tp < T) {
            lpb_f[k] = lp_s[tp * NCLS + 48];
            lpl_f[k] = lp_s[tp * NCLS + lidx];
        }

        float pa1 = dpp_shr1_neg(a1);           // alpha[2l-1] from lane l-1

        // state 2l: lse2(a0, pa1) + lpb  ((m0+lpb) runs parallel to exp/log)
        float m0 = fmaxf(a0, pa1);
        float n0 = fminf(a0, pa1);
        float r0 = (m0 + lpb) + log2f(1.0f + exp2f(n0 - m0));

        // state 2l+1: lse3(a1, a0, allow2 ? pa1 : NEG) + lpl
        float c12 = allow2 ? pa1 : NEGV;
        float m1 = fmaxf(fmaxf(a1, a0), c12);
        float r1 = (m1 + lpl) + log2f(exp2f(a1 - m1) + exp2f(a0 - m1) +
                                      exp2f(c12 - m1));

        a0 = r0;
        a1 = (lane < L) ? r1 : NEGV;            // states beyond S stay dead
    }

    float ab = __shfl(a0, ll);          // alpha[2*ll]
    float al = __shfl(a1, ll - 1);      // alpha[2*ll-1]
    if (lane == 0) {
        float m = fmaxf(ab, al);
        float ll2 = m + log2f(exp2f(ab - m) + exp2f(al - m));
        out[b] = -ll2 * 0.69314718055994531f;   // back to natural log
    }
}

// ---------------- Fallback: fused single kernel (small ws) ----------------
__global__ __launch_bounds__(256) void ctc_fused_kernel(
    const int* __restrict__ y_true,
    const float* __restrict__ y_pred,
    const int* __restrict__ label_len,
    float* __restrict__ out)
{
    const int b = blockIdx.x;
    const int tid = threadIdx.x;

    __shared__ float lp_s[T * NCLS + 32];
    __shared__ int   lab_s[L];
    __shared__ int   ll_s;

    if (tid < L) {
        int ll = label_len[b];
        if (tid == 0) ll_s = ll;
        int v = y_true[b * L + tid];
        lab_s[tid] = (tid < ll) ? v : BLANK;
    }
    __syncthreads();

    const float* yp = y_pred + (size_t)b * T * C;
    for (int g = tid; g < T * NCLS; g += 256) {
        int t = g / NCLS;
        int j = g - t * NCLS;
        int cls = (j < L) ? lab_s[j] : BLANK;
        lp_s[g] = log2f(yp[t * C + cls] + EPSV);
    }
    __syncthreads();

    if (tid >= 64) return;
    const int lane = tid;
    const int ll = ll_s;
    const int myLab   = (lane < L) ? lab_s[lane] : BLANK;
    const int prevLab = (lane >= 1 && lane - 1 < L) ? lab_s[lane - 1] : BLANK;
    const bool allow2 = (lane >= 1) && (myLab != BLANK) && (myLab != prevLab);

    float a0 = (lane == 0) ? lp_s[48] : NEGV;
    float a1 = (lane == 0) ? lp_s[0]  : NEGV;

    for (int t = 1; t < T; ++t) {
        float lpb = lp_s[t * NCLS + 48];
        float lpl = (lane < L) ? lp_s[t * NCLS + lane] : 0.0f;

        float pa1 = dpp_shr1_neg(a1);

        float m0 = fmaxf(a0, pa1);
        float n0 = fminf(a0, pa1);
        float r0 = (m0 + lpb) + log2f(1.0f + exp2f(n0 - m0));

        float c12 = allow2 ? pa1 : NEGV;
        float m1 = fmaxf(fmaxf(a1, a0), c12);
        float r1 = (m1 + lpl) + log2f(exp2f(a1 - m1) + exp2f(a0 - m1) +
                                      exp2f(c12 - m1));

        a0 = r0;
        a1 = (lane < L) ? r1 : NEGV;
    }

    float ab = __shfl(a0, ll);
    float al = __shfl(a1, ll - 1);
    if (lane == 0) {
        float m = fmaxf(ab, al);
        float ll2 = m + log2f(exp2f(ab - m) + exp2f(al - m));
        out[b] = -ll2 * 0.69314718055994531f;
    }
}

extern "C" void kernel_launch(void* const* d_in, const int* in_sizes, int n_in,
                              void* d_out, int out_size, void* d_ws, size_t ws_size,
                              hipStream_t stream) {
    const int*   y_true       = (const int*)d_in[0];
    const float* y_pred       = (const float*)d_in[1];
    const int*   label_length = (const int*)d_in[2];
    float*       out          = (float*)d_out;

    const size_t need = (size_t)TOTAL * sizeof(float) + (size_t)B * NCLS * sizeof(int);
    if (ws_size >= need) {
        float* lp_ws   = (float*)d_ws;
        int*   cls_tab = (int*)((char*)d_ws + (size_t)TOTAL * sizeof(float));
        cls_kernel<<<B, 64, 0, stream>>>(y_true, label_length, cls_tab);
        gather4_kernel<<<TOTAL / 1024, 256, 0, stream>>>(cls_tab, y_pred, lp_ws);
        dp_kernel<<<B, 64, 0, stream>>>(cls_tab, label_length, lp_ws, out);
    } else {
        ctc_fused_kernel<<<B, 256, 0, stream>>>(y_true, y_pred, label_length, out);
    }
}

// Round 6
// 34.523 us; speedup vs baseline: 1.4072x; 1.0680x over previous
//
#include <hip/hip_runtime.h>
#include <math.h>

// CTC batch cost. Two-kernel pipeline (round-3 structure, upgraded K2):
//  K1 (1568 blocks): random-gather log2(y_pred[b,t,cls]+eps) -> ws,
//     one gather per thread (full-chip, miss-queue parallelism maximal).
//  K2 (64 blocks x 256): stage [T][49] slice into LDS with 4 waves, then
//     wave-0 register DP over T; DPP wave_shr:1; prefetch distance 4 with
//     compile-time slot indices.
// Falls back to a fused single kernel if ws_size is too small.

#define NEGV (-1e30f)
#define EPSV (1e-7f)

constexpr int B = 64, T = 128, C = 4000, L = 48;
constexpr int BLANK = C - 1;       // 3999
constexpr int NCLS = L + 1;        // 49: slots 0..47 = labels, 48 = blank
constexpr int TOTAL = B * T * NCLS;  // 401408

// lane shift up by 1 via DPP wave_shr:1 (VALU latency). Lane 0 gets `old`.
__device__ __forceinline__ float dpp_shr1_neg(float x) {
    int r = __builtin_amdgcn_update_dpp(__float_as_int(NEGV), __float_as_int(x),
                                        0x138 /*wave_shr:1*/, 0xF, 0xF, false);
    return __int_as_float(r);
}
__device__ __forceinline__ int dpp_shr1_i(int x, int old) {
    return __builtin_amdgcn_update_dpp(old, x, 0x138, 0xF, 0xF, false);
}

// ---------------- Kernel 1: gather (round-3 verbatim, log2 domain) --------
__global__ __launch_bounds__(256) void gather_kernel(
    const int* __restrict__ y_true,     // [B, L]
    const float* __restrict__ y_pred,   // [B, T, C]
    const int* __restrict__ label_len,  // [B, 1]
    float* __restrict__ lp_ws)          // [B, T, NCLS] log2-probs
{
    int idx = blockIdx.x * 256 + threadIdx.x;
    if (idx >= TOTAL) return;
    int j  = idx % NCLS;
    int bt = idx / NCLS;
    int b  = bt / T;
    int cls = BLANK;
    if (j < L) {
        int ll = label_len[b];
        cls = (j < ll) ? y_true[b * L + j] : BLANK;
    }
    float p = y_pred[(size_t)bt * C + cls];
    lp_ws[idx] = log2f(p + EPSV);
}

// ---------------- Kernel 2: DP ----------------
__global__ __launch_bounds__(256) void dp_kernel(
    const int* __restrict__ y_true,
    const int* __restrict__ label_len,
    const float* __restrict__ lp_ws,    // [B, T, NCLS]
    float* __restrict__ out)            // [B, 1]
{
    const int b = blockIdx.x;
    const int tid = threadIdx.x;

    __shared__ float lp_s[T * NCLS + 32];   // pad: lane reads stay in-bounds

    // 4-wave coalesced stage: 1568 float4
    const float4* src = (const float4*)(lp_ws + (size_t)b * T * NCLS);
    float4* dst = (float4*)lp_s;
    for (int i = tid; i < (T * NCLS) / 4; i += 256) dst[i] = src[i];
    __syncthreads();

    if (tid >= 64) return;              // DP on wave 0 only
    const int lane = tid;

    const int ll = label_len[b];        // uniform, L2-hot
    int myLab = BLANK;
    if (lane < L) {
        int v = y_true[b * L + lane];
        myLab = (lane < ll) ? v : BLANK;
    }
    const int prevLab = dpp_shr1_i(myLab, BLANK);
    const bool allow2 = (lane >= 1) && (myLab != BLANK) && (myLab != prevLab);

    float a0 = (lane == 0) ? lp_s[48] : NEGV;   // t=0, state 0 (blank)
    float a1 = (lane == 0) ? lp_s[0]  : NEGV;   // t=0, state 1 (label 0)

    const int lidx = (lane < NCLS) ? lane : 48;

    // rolling prefetch file, distance 4, all indices compile-time
    float lpb_f[4], lpl_f[4];
    #pragma unroll
    for (int k = 0; k < 4; ++k) {
        lpb_f[k] = lp_s[(1 + k) * NCLS + 48];
        lpl_f[k] = lp_s[(1 + k) * NCLS + lidx];
    }

    for (int tb = 1; tb < T; tb += 4) {
        #pragma unroll
        for (int u = 0; u < 4; ++u) {
            int t = tb + u;
            if (t >= T) break;          // tb pattern: only last block trims
            float lpb = lpb_f[u];
            float lpl = lpl_f[u];       // junk for lane>=L; result discarded
            int tp = t + 4;
            if (tp < T) {
                lpb_f[u] = lp_s[tp * NCLS + 48];
                lpl_f[u] = lp_s[tp * NCLS + lidx];
            }

            float pa1 = dpp_shr1_neg(a1);   // alpha[2l-1] from lane l-1

            // state 2l: lse2(a0, pa1) + lpb
            float m0 = fmaxf(a0, pa1);
            float n0 = fminf(a0, pa1);
            float r0 = (m0 + lpb) + log2f(1.0f + exp2f(n0 - m0));

            // state 2l+1: lse3(a1, a0, allow2 ? pa1 : NEG) + lpl
            float c12 = allow2 ? pa1 : NEGV;
            float m1 = fmaxf(fmaxf(a1, a0), c12);   // -> v_max3_f32
            float r1 = (m1 + lpl) + log2f(exp2f(a1 - m1) + exp2f(a0 - m1) +
                                          exp2f(c12 - m1));

            a0 = r0;
            a1 = (lane < L) ? r1 : NEGV;    // states beyond S stay dead
        }
    }

    float ab = __shfl(a0, ll);          // alpha[2*ll]
    float al = __shfl(a1, ll - 1);      // alpha[2*ll-1]
    if (lane == 0) {
        float m = fmaxf(ab, al);
        float ll2 = m + log2f(exp2f(ab - m) + exp2f(al - m));
        out[b] = -ll2 * 0.69314718055994531f;   // back to natural log
    }
}

// ---------------- Fallback: fused single kernel (small ws) ----------------
__global__ __launch_bounds__(256) void ctc_fused_kernel(
    const int* __restrict__ y_true,
    const float* __restrict__ y_pred,
    const int* __restrict__ label_len,
    float* __restrict__ out)
{
    const int b = blockIdx.x;
    const int tid = threadIdx.x;

    __shared__ float lp_s[T * NCLS + 32];
    __shared__ int   lab_s[L];
    __shared__ int   ll_s;

    if (tid < L) {
        int ll = label_len[b];
        if (tid == 0) ll_s = ll;
        int v = y_true[b * L + tid];
        lab_s[tid] = (tid < ll) ? v : BLANK;
    }
    __syncthreads();

    const float* yp = y_pred + (size_t)b * T * C;
    for (int g = tid; g < T * NCLS; g += 256) {
        int t = g / NCLS;
        int j = g - t * NCLS;
        int cls = (j < L) ? lab_s[j] : BLANK;
        lp_s[g] = log2f(yp[t * C + cls] + EPSV);
    }
    __syncthreads();

    if (tid >= 64) return;
    const int lane = tid;
    const int ll = ll_s;
    const int myLab   = (lane < L) ? lab_s[lane] : BLANK;
    const int prevLab = (lane >= 1 && lane - 1 < L) ? lab_s[lane - 1] : BLANK;
    const bool allow2 = (lane >= 1) && (myLab != BLANK) && (myLab != prevLab);

    float a0 = (lane == 0) ? lp_s[48] : NEGV;
    float a1 = (lane == 0) ? lp_s[0]  : NEGV;

    for (int t = 1; t < T; ++t) {
        float lpb = lp_s[t * NCLS + 48];
        float lpl = (lane < L) ? lp_s[t * NCLS + lane] : 0.0f;

        float pa1 = dpp_shr1_neg(a1);

        float m0 = fmaxf(a0, pa1);
        float n0 = fminf(a0, pa1);
        float r0 = (m0 + lpb) + log2f(1.0f + exp2f(n0 - m0));

        float c12 = allow2 ? pa1 : NEGV;
        float m1 = fmaxf(fmaxf(a1, a0), c12);
        float r1 = (m1 + lpl) + log2f(exp2f(a1 - m1) + exp2f(a0 - m1) +
                                      exp2f(c12 - m1));

        a0 = r0;
        a1 = (lane < L) ? r1 : NEGV;
    }

    float ab = __shfl(a0, ll);
    float al = __shfl(a1, ll - 1);
    if (lane == 0) {
        float m = fmaxf(ab, al);
        float ll2 = m + log2f(exp2f(ab - m) + exp2f(al - m));
        out[b] = -ll2 * 0.69314718055994531f;
    }
}

extern "C" void kernel_launch(void* const* d_in, const int* in_sizes, int n_in,
                              void* d_out, int out_size, void* d_ws, size_t ws_size,
                              hipStream_t stream) {
    const int*   y_true       = (const int*)d_in[0];
    const float* y_pred       = (const float*)d_in[1];
    const int*   label_length = (const int*)d_in[2];
    float*       out          = (float*)d_out;

    const size_t need = (size_t)TOTAL * sizeof(float);
    if (ws_size >= need) {
        float* lp_ws = (float*)d_ws;
        gather_kernel<<<(TOTAL + 255) / 256, 256, 0, stream>>>(
            y_true, y_pred, label_length, lp_ws);
        dp_kernel<<<B, 256, 0, stream>>>(y_true, label_length, lp_ws, out);
    } else {
        ctc_fused_kernel<<<B, 256, 0, stream>>>(y_true, y_pred, label_length, out);
    }
}

// Round 7
// 31.165 us; speedup vs baseline: 1.5589x; 1.1078x over previous
//
#include <hip/hip_runtime.h>
#include <math.h>

// CTC batch cost. Two-kernel pipeline (round-3 structure, K1 chain-shortened):
//  K1 (1568 blocks): random-gather log2(y_pred[b,t,cls]+eps) -> ws.
//     Block-shared class tables in LDS (a block spans <=2 batch rows), so the
//     per-thread dependent chain is LDS-read -> HBM gather instead of
//     L2 label_len -> L2 y_true -> HBM gather.
//  K2 (64 blocks x 256): round-3 verbatim DP (4-wave stage, wave-0 DP,
//     DPP wave_shr:1, prefetch distance 1).
// Falls back to a fused single kernel if ws_size is too small.

#define NEGV (-1e30f)
#define EPSV (1e-7f)

constexpr int B = 64, T = 128, C = 4000, L = 48;
constexpr int BLANK = C - 1;       // 3999
constexpr int NCLS = L + 1;        // 49: slots 0..47 = labels, 48 = blank
constexpr int TOTAL = B * T * NCLS;  // 401408 = 1568 * 256 exactly

// lane shift up by 1 via DPP wave_shr:1 (VALU latency). Lane 0 gets `old`.
__device__ __forceinline__ float dpp_shr1_neg(float x) {
    int r = __builtin_amdgcn_update_dpp(__float_as_int(NEGV), __float_as_int(x),
                                        0x138 /*wave_shr:1*/, 0xF, 0xF, false);
    return __int_as_float(r);
}
__device__ __forceinline__ int dpp_shr1_i(int x, int old) {
    return __builtin_amdgcn_update_dpp(old, x, 0x138, 0xF, 0xF, false);
}

// ---------------- Kernel 1: gather with block-shared class tables ---------
__global__ __launch_bounds__(256) void gather_kernel(
    const int* __restrict__ y_true,     // [B, L]
    const float* __restrict__ y_pred,   // [B, T, C]
    const int* __restrict__ label_len,  // [B, 1]
    float* __restrict__ lp_ws)          // [B, T, NCLS] log2-probs
{
    const int base = blockIdx.x * 256;
    const int tid  = threadIdx.x;
    const int idx  = base + tid;

    // batch rows covered by this block's 256 indices (at most 2)
    const int b0 = base / (T * NCLS);
    const int b1 = (base + 255) / (T * NCLS);

    __shared__ int cls_s[2 * NCLS];

    // two different waves build the two tables in parallel
    if (tid < NCLS) {
        int ll = label_len[b0];
        int cls = BLANK;
        if (tid < L) cls = (tid < ll) ? y_true[b0 * L + tid] : BLANK;
        cls_s[tid] = cls;
    } else if (tid >= 128 && tid < 128 + NCLS) {
        int j = tid - 128;
        int ll = label_len[b1];
        int cls = BLANK;
        if (j < L) cls = (j < ll) ? y_true[b1 * L + j] : BLANK;
        cls_s[NCLS + j] = cls;
    }
    __syncthreads();

    int bt = idx / NCLS;
    int j  = idx - bt * NCLS;
    int b  = bt >> 7;                   // / T
    int cls = cls_s[(b - b0) * NCLS + j];
    float p = y_pred[(size_t)bt * C + cls];   // the one HBM-latency hop
    lp_ws[idx] = log2f(p + EPSV);
}

// ---------------- Kernel 2: DP (round-3 verbatim) ----------------
__global__ __launch_bounds__(256) void dp_kernel(
    const int* __restrict__ y_true,
    const int* __restrict__ label_len,
    const float* __restrict__ lp_ws,    // [B, T, NCLS]
    float* __restrict__ out)            // [B, 1]
{
    const int b = blockIdx.x;
    const int tid = threadIdx.x;

    __shared__ float lp_s[T * NCLS + 32];
    __shared__ int   lab_s[L];
    __shared__ int   ll_s;

    if (tid < L) {
        int ll = label_len[b];
        if (tid == 0) ll_s = ll;
        int v = y_true[b * L + tid];
        lab_s[tid] = (tid < ll) ? v : BLANK;   // pad with blank as reference
    }

    // coalesced float4 stage: 6272 floats = 1568 float4
    const float4* src = (const float4*)(lp_ws + (size_t)b * T * NCLS);
    float4* dst = (float4*)lp_s;
    for (int i = tid; i < (T * NCLS) / 4; i += 256) dst[i] = src[i];
    __syncthreads();

    if (tid >= 64) return;              // DP on wave 0 only
    const int lane = tid;
    const int ll = ll_s;

    const int myLab   = (lane < L) ? lab_s[lane] : BLANK;
    const int prevLab = (lane >= 1 && lane - 1 < L) ? lab_s[lane - 1] : BLANK;
    const bool allow2 = (lane >= 1) && (myLab != BLANK) && (myLab != prevLab);

    float a0 = (lane == 0) ? lp_s[48] : NEGV;   // t=0, state 0 (blank)
    float a1 = (lane == 0) ? lp_s[0]  : NEGV;   // t=0, state 1 (label 0)

    // prefetch lp for t=1
    float lpb_n = lp_s[1 * NCLS + 48];
    float lpl_n = (lane < L) ? lp_s[1 * NCLS + lane] : 0.0f;

    for (int t = 1; t < T; ++t) {
        float lpb = lpb_n, lpl = lpl_n;
        int tn = (t + 1 < T) ? t + 1 : t;
        lpb_n = lp_s[tn * NCLS + 48];
        lpl_n = (lane < L) ? lp_s[tn * NCLS + lane] : 0.0f;

        float pa1 = dpp_shr1_neg(a1);   // alpha[2l-1] from lane l-1

        // state 2l: lse2(a0, pa1) + lpb
        float m0 = fmaxf(a0, pa1);
        float n0 = fminf(a0, pa1);
        float r0 = (m0 + lpb) + log2f(1.0f + exp2f(n0 - m0));

        // state 2l+1: lse3(a1, a0, allow2 ? pa1 : NEG) + lpl
        float c12 = allow2 ? pa1 : NEGV;
        float m1 = fmaxf(fmaxf(a1, a0), c12);
        float r1 = (m1 + lpl) + log2f(exp2f(a1 - m1) + exp2f(a0 - m1) +
                                      exp2f(c12 - m1));

        a0 = r0;
        a1 = (lane < L) ? r1 : NEGV;    // states beyond S stay dead
    }

    float ab = __shfl(a0, ll);          // alpha[2*ll]
    float al = __shfl(a1, ll - 1);      // alpha[2*ll-1]
    if (lane == 0) {
        float m = fmaxf(ab, al);
        float ll2 = m + log2f(exp2f(ab - m) + exp2f(al - m));
        out[b] = -ll2 * 0.69314718055994531f;   // back to natural log
    }
}

// ---------------- Fallback: fused single kernel (small ws) ----------------
__global__ __launch_bounds__(256) void ctc_fused_kernel(
    const int* __restrict__ y_true,
    const float* __restrict__ y_pred,
    const int* __restrict__ label_len,
    float* __restrict__ out)
{
    const int b = blockIdx.x;
    const int tid = threadIdx.x;

    __shared__ float lp_s[T * NCLS + 32];
    __shared__ int   lab_s[L];
    __shared__ int   ll_s;

    if (tid < L) {
        int ll = label_len[b];
        if (tid == 0) ll_s = ll;
        int v = y_true[b * L + tid];
        lab_s[tid] = (tid < ll) ? v : BLANK;
    }
    __syncthreads();

    const float* yp = y_pred + (size_t)b * T * C;
    for (int g = tid; g < T * NCLS; g += 256) {
        int t = g / NCLS;
        int j = g - t * NCLS;
        int cls = (j < L) ? lab_s[j] : BLANK;
        lp_s[g] = log2f(yp[t * C + cls] + EPSV);
    }
    __syncthreads();

    if (tid >= 64) return;
    const int lane = tid;
    const int ll = ll_s;
    const int myLab   = (lane < L) ? lab_s[lane] : BLANK;
    const int prevLab = (lane >= 1 && lane - 1 < L) ? lab_s[lane - 1] : BLANK;
    const bool allow2 = (lane >= 1) && (myLab != BLANK) && (myLab != prevLab);

    float a0 = (lane == 0) ? lp_s[48] : NEGV;
    float a1 = (lane == 0) ? lp_s[0]  : NEGV;

    for (int t = 1; t < T; ++t) {
        float lpb = lp_s[t * NCLS + 48];
        float lpl = (lane < L) ? lp_s[t * NCLS + lane] : 0.0f;

        float pa1 = dpp_shr1_neg(a1);

        float m0 = fmaxf(a0, pa1);
        float n0 = fminf(a0, pa1);
        float r0 = (m0 + lpb) + log2f(1.0f + exp2f(n0 - m0));

        float c12 = allow2 ? pa1 : NEGV;
        float m1 = fmaxf(fmaxf(a1, a0), c12);
        float r1 = (m1 + lpl) + log2f(exp2f(a1 - m1) + exp2f(a0 - m1) +
                                      exp2f(c12 - m1));

        a0 = r0;
        a1 = (lane < L) ? r1 : NEGV;
    }

    float ab = __shfl(a0, ll);
    float al = __shfl(a1, ll - 1);
    if (lane == 0) {
        float m = fmaxf(ab, al);
        float ll2 = m + log2f(exp2f(ab - m) + exp2f(al - m));
        out[b] = -ll2 * 0.69314718055994531f;
    }
}

extern "C" void kernel_launch(void* const* d_in, const int* in_sizes, int n_in,
                              void* d_out, int out_size, void* d_ws, size_t ws_size,
                              hipStream_t stream) {
    const int*   y_true       = (const int*)d_in[0];
    const float* y_pred       = (const float*)d_in[1];
    const int*   label_length = (const int*)d_in[2];
    float*       out          = (float*)d_out;

    const size_t need = (size_t)TOTAL * sizeof(float);
    if (ws_size >= need) {
        float* lp_ws = (float*)d_ws;
        gather_kernel<<<TOTAL / 256, 256, 0, stream>>>(
            y_true, y_pred, label_length, lp_ws);
        dp_kernel<<<B, 256, 0, stream>>>(y_true, label_length, lp_ws, out);
    } else {
        ctc_fused_kernel<<<B, 256, 0, stream>>>(y_true, y_pred, label_length, out);
    }
}